// Round 6
// baseline (232.614 us; speedup 1.0000x reference)
//
#include <hip/hip_runtime.h>
#include <math.h>

#define D 128
#define BN_EPS 1e-3f
#define L2_EPS 1e-12f

typedef unsigned int uint;
typedef unsigned short ushort;
typedef __attribute__((ext_vector_type(8))) short bf16x8;  // 8 bf16 in 4 VGPRs
typedef __attribute__((ext_vector_type(4))) float f32x4;

__device__ __forceinline__ ushort f2bf(float f) {
  uint u = __float_as_uint(f);
  uint r = (u + 0x7fffu + ((u >> 16) & 1u)) >> 16;
  return (ushort)r;
}
__device__ __forceinline__ float bflo(uint u) { return __uint_as_float(u << 16); }
__device__ __forceinline__ float bfhi(uint u) { return __uint_as_float(u & 0xffff0000u); }
__device__ __forceinline__ float bf2f(ushort h) { return __uint_as_float(((uint)h) << 16); }

// ---------------------------------------------------------------------------
// Device helpers for the fused prep kernel
// ---------------------------------------------------------------------------
__device__ __forceinline__ void pack_bfrag_block(
    const float* __restrict__ W, const float* __restrict__ gamma,
    const float* __restrict__ var, ushort* __restrict__ Bf, int blk, int tid) {
  int t = blk * 256 + tid;  // 0..2047
  int f = t >> 6, lane = t & 63;
  int kc = f >> 3, nt = f & 7, q = lane >> 4, m = lane & 15;
  ushort tmp[8];
#pragma unroll
  for (int j = 0; j < 8; ++j) {
    int k = kc * 32 + q * 8 + j;
    float s = gamma[k] * rsqrtf(var[k] + BN_EPS);
    tmp[j] = f2bf(s * W[k * D + nt * 16 + m]);
  }
  uint4 o;
  o.x = (uint)tmp[0] | ((uint)tmp[1] << 16);
  o.y = (uint)tmp[2] | ((uint)tmp[3] << 16);
  o.z = (uint)tmp[4] | ((uint)tmp[5] << 16);
  o.w = (uint)tmp[6] | ((uint)tmp[7] << 16);
  reinterpret_cast<uint4*>(Bf)[t] = o;
}

__device__ __forceinline__ void bn_bias_block(
    const float* __restrict__ W, const float* __restrict__ gamma,
    const float* __restrict__ beta, const float* __restrict__ mean,
    const float* __restrict__ var, float* __restrict__ outb, int j) {
  float acc = 0.f;
  for (int k = 0; k < D; ++k) {
    float s = gamma[k] * rsqrtf(var[k] + BN_EPS);
    float sh = beta[k] - mean[k] * s;
    acc += sh * W[k * D + j];
  }
  outb[j] = acc;
}

// ---------------------------------------------------------------------------
// Fused prep: [0,nbConv) f32->bf16 | [+nbRp) row_ptr | +8 Bf1 | +8 Bf2 |
// +1 bnb | +1 shd | rest: packed edge arrays ew1=(col,adj),
// ew2=(col, adj/(relc[rel]+1)), one pad entry (0,0) at index e.
// ---------------------------------------------------------------------------
__global__ __launch_bounds__(256) void prep_kernel(
    const float* __restrict__ x, ushort* __restrict__ xbf, int n4,
    const int* __restrict__ rows, int* __restrict__ row_ptr, int n, int e,
    const float* __restrict__ W1, const float* __restrict__ g1,
    const float* __restrict__ v1, ushort* __restrict__ Bf1,
    const float* __restrict__ Wd, const float* __restrict__ g2,
    const float* __restrict__ v2, ushort* __restrict__ Bf2,
    const float* __restrict__ beta1, const float* __restrict__ mean1,
    float* __restrict__ bnb,
    const float* __restrict__ beta2, const float* __restrict__ mean2,
    float* __restrict__ shd,
    const int* __restrict__ cols, const float* __restrict__ adj,
    const int* __restrict__ rel, const float* __restrict__ relc,
    uint2* __restrict__ ew1, uint2* __restrict__ ew2,
    int nbConv, int nbRp) {
  const int b = blockIdx.x, tid = threadIdx.x;
  if (b < nbConv) {
    int i = b * 256 + tid;
    if (i < n4) {
      float4 v = reinterpret_cast<const float4*>(x)[i];
      ushort4 o;
      o.x = f2bf(v.x); o.y = f2bf(v.y); o.z = f2bf(v.z); o.w = f2bf(v.w);
      reinterpret_cast<ushort4*>(xbf)[i] = o;
    }
    return;
  }
  int bb = b - nbConv;
  if (bb < nbRp) {
    int i = bb * 256 + tid;
    if (i <= n) {
      int lo = 0, hi = e;
      while (lo < hi) {
        int mid = (lo + hi) >> 1;
        if (rows[mid] < i) lo = mid + 1; else hi = mid;
      }
      row_ptr[i] = lo;
    }
    return;
  }
  bb -= nbRp;
  if (bb < 8) { pack_bfrag_block(W1, g1, v1, Bf1, bb, tid); return; }
  if (bb < 16) { pack_bfrag_block(Wd, g2, v2, Bf2, bb - 8, tid); return; }
  if (bb == 16) { if (tid < D) bn_bias_block(W1, g1, beta1, mean1, v1, bnb, tid); return; }
  if (bb == 17) { if (tid < D) bn_bias_block(Wd, g2, beta2, mean2, v2, shd, tid); return; }
  int i = (bb - 18) * 256 + tid;
  if (i < e) {
    uint c = (uint)cols[i];
    float a = adj[i];
    ew1[i] = make_uint2(c, __float_as_uint(a));
    float w2 = a / (relc[rel[i]] + 1.0f);
    ew2[i] = make_uint2(c, __float_as_uint(w2));
  } else if (i == e) {
    ew1[i] = make_uint2(0u, 0u);
    ew2[i] = make_uint2(0u, 0u);
  }
}

// ---------------------------------------------------------------------------
// SpMM phase (device fn): wave handles 16 rows in 4 passes of 4 rows
// (16 lanes/row, one uint4 = 8 bf16 gather per lane per edge). Masked
// unroll-4 with metadata prefetch (next quad's 8 B meta loads issue before
// current quad's FMAs -> meta latency off the gather critical path).
// Results -> LDS aggL (bf16, row stride 17 uint4 to break bank aliasing),
// rowsums -> LDS rsL.
// ---------------------------------------------------------------------------
template <bool SELF>
__device__ __forceinline__ void spmm_phase(
    const uint4* __restrict__ S4, const int* __restrict__ row_ptr,
    const uint2* __restrict__ ew, const float* __restrict__ ck,
    int n, int blockRow0, uint4* aggL, float* rsL) {
  const int lane = threadIdx.x & 63;
  const int wave = threadIdx.x >> 6;
  const int g = lane >> 4, m = lane & 15;
#pragma unroll
  for (int p = 0; p < 4; ++p) {
    const int rblk = wave * 16 + p * 4 + g;
    const int r = blockRow0 + rblk;
    const int rr = r < n ? r : n - 1;
    const int e0 = row_ptr[rr];
    int len = row_ptr[rr + 1] - e0;
    if (r >= n) len = 0;
    int mx = len;
    mx = max(mx, __shfl_xor(mx, 16));
    mx = max(mx, __shfl_xor(mx, 32));
    const int lastOff = len > 0 ? len - 1 : 0;

    float acc[8] = {0.f, 0.f, 0.f, 0.f, 0.f, 0.f, 0.f, 0.f};
    float ws = 0.f;

    uint2 md[4];
#pragma unroll
    for (int u = 0; u < 4; ++u) {
      int off = u < len ? u : lastOff;
      md[u] = ew[e0 + off];
    }
    for (int i = 0; i < mx; i += 4) {
      uint4 gv[4];
#pragma unroll
      for (int u = 0; u < 4; ++u) gv[u] = S4[(size_t)md[u].x * 16 + m];
      uint2 mdn[4];
#pragma unroll
      for (int u = 0; u < 4; ++u) {
        int ii = i + 4 + u;
        int off = ii < len ? ii : lastOff;
        mdn[u] = ew[e0 + off];
      }
#pragma unroll
      for (int u = 0; u < 4; ++u) {
        float w = (i + u) < len ? __uint_as_float(md[u].y) : 0.f;
        ws += w;
        acc[0] = fmaf(w, bflo(gv[u].x), acc[0]);
        acc[1] = fmaf(w, bfhi(gv[u].x), acc[1]);
        acc[2] = fmaf(w, bflo(gv[u].y), acc[2]);
        acc[3] = fmaf(w, bfhi(gv[u].y), acc[3]);
        acc[4] = fmaf(w, bflo(gv[u].z), acc[4]);
        acc[5] = fmaf(w, bfhi(gv[u].z), acc[5]);
        acc[6] = fmaf(w, bflo(gv[u].w), acc[6]);
        acc[7] = fmaf(w, bfhi(gv[u].w), acc[7]);
      }
#pragma unroll
      for (int u = 0; u < 4; ++u) md[u] = mdn[u];
    }
    if (SELF) {
      uint4 us = S4[(size_t)rr * 16 + m];
      float cp = ck[rr] + 1.0f;
      acc[0] = fmaf(cp, bflo(us.x), acc[0]);
      acc[1] = fmaf(cp, bfhi(us.x), acc[1]);
      acc[2] = fmaf(cp, bflo(us.y), acc[2]);
      acc[3] = fmaf(cp, bfhi(us.y), acc[3]);
      acc[4] = fmaf(cp, bflo(us.z), acc[4]);
      acc[5] = fmaf(cp, bfhi(us.z), acc[5]);
      acc[6] = fmaf(cp, bflo(us.w), acc[6]);
      acc[7] = fmaf(cp, bfhi(us.w), acc[7]);
    }
    uint4 o;
    o.x = (uint)f2bf(acc[0]) | ((uint)f2bf(acc[1]) << 16);
    o.y = (uint)f2bf(acc[2]) | ((uint)f2bf(acc[3]) << 16);
    o.z = (uint)f2bf(acc[4]) | ((uint)f2bf(acc[5]) << 16);
    o.w = (uint)f2bf(acc[6]) | ((uint)f2bf(acc[7]) << 16);
    aggL[rblk * 17 + m] = o;
    if (m == 0) rsL[rblk] = ws;
  }
}

// ---------------------------------------------------------------------------
// Fused layer 1: spmm(x) -> LDS -> MFMA GEMM -> y1 = tanh(.. + rs*bnb + b1).
// ---------------------------------------------------------------------------
__global__ __launch_bounds__(256) void fused1_kernel(
    const ushort* __restrict__ xbf, const int* __restrict__ row_ptr,
    const uint2* __restrict__ ew1, const ushort* __restrict__ Bf,
    const float* __restrict__ bnb, const float* __restrict__ b1,
    ushort* __restrict__ y1, int n) {
  __shared__ uint4 aggL[64 * 17];
  __shared__ float rsL[64];
  const int blockRow0 = blockIdx.x * 64;
  spmm_phase<false>(reinterpret_cast<const uint4*>(xbf), row_ptr, ew1,
                    nullptr, n, blockRow0, aggL, rsL);
  __syncthreads();

  const int wave = threadIdx.x >> 6, lane = threadIdx.x & 63;
  const int m = lane & 15, q = lane >> 4;
  const int row = blockRow0 + wave * 16 + m;
  const bf16x8* Bv = reinterpret_cast<const bf16x8*>(Bf);

  bf16x8 af[4];
#pragma unroll
  for (int kc = 0; kc < 4; ++kc)
    af[kc] = *reinterpret_cast<const bf16x8*>(&aggL[(wave * 16 + m) * 17 + kc * 4 + q]);

  f32x4 acc[8];
#pragma unroll
  for (int nt = 0; nt < 8; ++nt) acc[nt] = (f32x4){0.f, 0.f, 0.f, 0.f};
#pragma unroll
  for (int kc = 0; kc < 4; ++kc) {
#pragma unroll
    for (int nt = 0; nt < 8; ++nt) {
      bf16x8 b = Bv[(kc * 8 + nt) * 64 + lane];
      acc[nt] = __builtin_amdgcn_mfma_f32_16x16x32_bf16(b, af[kc], acc[nt], 0, 0, 0);
    }
  }

  if (row < n) {
    float rs = rsL[wave * 16 + m];
#pragma unroll
    for (int nt = 0; nt < 8; ++nt) {
      const float4 bn = *reinterpret_cast<const float4*>(&bnb[nt * 16 + q * 4]);
      const float4 bb = *reinterpret_cast<const float4*>(&b1[nt * 16 + q * 4]);
      ushort4 o;
      o.x = f2bf(tanhf(acc[nt][0] + rs * bn.x + bb.x));
      o.y = f2bf(tanhf(acc[nt][1] + rs * bn.y + bb.y));
      o.z = f2bf(tanhf(acc[nt][2] + rs * bn.z + bb.z));
      o.w = f2bf(tanhf(acc[nt][3] + rs * bn.w + bb.w));
      *reinterpret_cast<ushort4*>(&y1[(size_t)row * D + nt * 16 + q * 4]) = o;
    }
  }
}

// ---------------------------------------------------------------------------
// Fused layer 2 + finalize: spmm(y1, rel-weighted, +self) -> LDS -> MFMA ->
// y2 = .. + (rs+ck+1)*shd + bd, then out = l2n([l2n(x),l2n(y1),l2n(y2)]).
// ---------------------------------------------------------------------------
__global__ __launch_bounds__(256) void fused2_kernel(
    const ushort* __restrict__ y1, const int* __restrict__ row_ptr,
    const uint2* __restrict__ ew2, const float* __restrict__ ck,
    const ushort* __restrict__ Bf, const float* __restrict__ shd,
    const float* __restrict__ bd, const float* __restrict__ x,
    float* __restrict__ out, int n) {
  __shared__ uint4 aggL[64 * 17];
  __shared__ float rsL[64];
  const int blockRow0 = blockIdx.x * 64;
  spmm_phase<true>(reinterpret_cast<const uint4*>(y1), row_ptr, ew2,
                   ck, n, blockRow0, aggL, rsL);
  __syncthreads();

  const int wave = threadIdx.x >> 6, lane = threadIdx.x & 63;
  const int m = lane & 15, q = lane >> 4;
  const int row = blockRow0 + wave * 16 + m;
  const int arow = row < n ? row : n - 1;
  const bf16x8* Bv = reinterpret_cast<const bf16x8*>(Bf);

  bf16x8 af[4];
#pragma unroll
  for (int kc = 0; kc < 4; ++kc)
    af[kc] = *reinterpret_cast<const bf16x8*>(&aggL[(wave * 16 + m) * 17 + kc * 4 + q]);

  f32x4 acc[8];
#pragma unroll
  for (int nt = 0; nt < 8; ++nt) acc[nt] = (f32x4){0.f, 0.f, 0.f, 0.f};
#pragma unroll
  for (int kc = 0; kc < 4; ++kc) {
#pragma unroll
    for (int nt = 0; nt < 8; ++nt) {
      bf16x8 b = Bv[(kc * 8 + nt) * 64 + lane];
      acc[nt] = __builtin_amdgcn_mfma_f32_16x16x32_bf16(b, af[kc], acc[nt], 0, 0, 0);
    }
  }

  const float rb = rsL[wave * 16 + m] + ck[arow] + 1.0f;
  float4 xv[8];
  ushort4 y1v[8];
  float s0 = 0.f, s1 = 0.f, s2 = 0.f;
#pragma unroll
  for (int nt = 0; nt < 8; ++nt) {
    const float4 sh = *reinterpret_cast<const float4*>(&shd[nt * 16 + q * 4]);
    const float4 bb = *reinterpret_cast<const float4*>(&bd[nt * 16 + q * 4]);
    acc[nt][0] += rb * sh.x + bb.x;
    acc[nt][1] += rb * sh.y + bb.y;
    acc[nt][2] += rb * sh.z + bb.z;
    acc[nt][3] += rb * sh.w + bb.w;
    s2 += acc[nt][0] * acc[nt][0] + acc[nt][1] * acc[nt][1] +
          acc[nt][2] * acc[nt][2] + acc[nt][3] * acc[nt][3];
    xv[nt] = *reinterpret_cast<const float4*>(&x[(size_t)arow * D + nt * 16 + q * 4]);
    s0 += xv[nt].x * xv[nt].x + xv[nt].y * xv[nt].y +
          xv[nt].z * xv[nt].z + xv[nt].w * xv[nt].w;
    y1v[nt] = *reinterpret_cast<const ushort4*>(&y1[(size_t)arow * D + nt * 16 + q * 4]);
    float ya = bf2f(y1v[nt].x), yb = bf2f(y1v[nt].y);
    float yc = bf2f(y1v[nt].z), yd = bf2f(y1v[nt].w);
    s1 += ya * ya + yb * yb + yc * yc + yd * yd;
  }
  s0 += __shfl_xor(s0, 16); s0 += __shfl_xor(s0, 32);
  s1 += __shfl_xor(s1, 16); s1 += __shfl_xor(s1, 32);
  s2 += __shfl_xor(s2, 16); s2 += __shfl_xor(s2, 32);
  const float i0 = 1.0f / sqrtf(fmaxf(s0, L2_EPS));
  const float i1 = 1.0f / sqrtf(fmaxf(s1, L2_EPS));
  const float i2 = 1.0f / sqrtf(fmaxf(s2, L2_EPS));
  const float tot = s0 * i0 * i0 + s1 * i1 * i1 + s2 * i2 * i2;
  const float sc = 1.0f / sqrtf(fmaxf(tot, L2_EPS));
  const float f0 = i0 * sc, f1 = i1 * sc, f2 = i2 * sc;

  if (row < n) {
    float* orow = out + (size_t)row * 384;
#pragma unroll
    for (int nt = 0; nt < 8; ++nt) {
      const int c = nt * 16 + q * 4;
      float4 ox = make_float4(xv[nt].x * f0, xv[nt].y * f0, xv[nt].z * f0, xv[nt].w * f0);
      float4 oy = make_float4(bf2f(y1v[nt].x) * f1, bf2f(y1v[nt].y) * f1,
                              bf2f(y1v[nt].z) * f1, bf2f(y1v[nt].w) * f1);
      float4 oz = make_float4(acc[nt][0] * f2, acc[nt][1] * f2,
                              acc[nt][2] * f2, acc[nt][3] * f2);
      *reinterpret_cast<float4*>(orow + c) = ox;
      *reinterpret_cast<float4*>(orow + 128 + c) = oy;
      *reinterpret_cast<float4*>(orow + 256 + c) = oz;
    }
  }
}

// ---------------------------------------------------------------------------
extern "C" void kernel_launch(void* const* d_in, const int* in_sizes, int n_in,
                              void* d_out, int out_size, void* d_ws, size_t ws_size,
                              hipStream_t stream) {
  const float* x      = (const float*)d_in[0];
  const int*   rows   = (const int*)d_in[1];
  const int*   cols   = (const int*)d_in[2];
  const float* adj    = (const float*)d_in[3];
  const int*   rel    = (const int*)d_in[4];
  const float* gamma1 = (const float*)d_in[5];
  const float* beta1  = (const float*)d_in[6];
  const float* mean1  = (const float*)d_in[7];
  const float* var1   = (const float*)d_in[8];
  const float* W1     = (const float*)d_in[9];
  const float* b1     = (const float*)d_in[10];
  const float* gamma2 = (const float*)d_in[11];
  const float* beta2  = (const float*)d_in[12];
  const float* mean2  = (const float*)d_in[13];
  const float* var2   = (const float*)d_in[14];
  const float* relc   = (const float*)d_in[15];
  const float* ck     = (const float*)d_in[16];
  const float* Wd     = (const float*)d_in[17];
  const float* bd     = (const float*)d_in[18];
  float* out = (float*)d_out;

  const int n = in_sizes[0] / D;
  const int e = in_sizes[1];
  size_t nd = (size_t)n * D;

  char* p = (char*)d_ws;
  ushort* xbf   = (ushort*)p; p += nd * 2;
  ushort* y1bf  = (ushort*)p; p += nd * 2;
  ushort* Bf1   = (ushort*)p; p += 32768;
  ushort* Bf2   = (ushort*)p; p += 32768;
  float*  bnb   = (float*)p;  p += 512;
  float*  shd   = (float*)p;  p += 512;
  p = (char*)(((uintptr_t)p + 15) & ~(uintptr_t)15);
  uint2* ew1    = (uint2*)p;  p += (size_t)(e + 1) * 8;
  uint2* ew2    = (uint2*)p;  p += (size_t)(e + 1) * 8;
  int* row_ptr  = (int*)p;    p += (size_t)(n + 1) * 4;

  const int n4 = (int)(nd / 4);
  const int nbConv = (n4 + 255) / 256;
  const int nbRp = (n + 1 + 255) / 256;
  const int nbEw = (e + 1 + 255) / 256;
  const int nbPrep = nbConv + nbRp + 18 + nbEw;

  prep_kernel<<<nbPrep, 256, 0, stream>>>(
      x, xbf, n4, rows, row_ptr, n, e,
      W1, gamma1, var1, Bf1, Wd, gamma2, var2, Bf2,
      beta1, mean1, bnb, beta2, mean2, shd,
      cols, adj, rel, relc, ew1, ew2, nbConv, nbRp);

  int fblocks = (n + 63) / 64;
  fused1_kernel<<<fblocks, 256, 0, stream>>>(
      xbf, row_ptr, ew1, Bf1, bnb, b1, y1bf, n);
  fused2_kernel<<<fblocks, 256, 0, stream>>>(
      y1bf, row_ptr, ew2, ck, Bf2, shd, bd, x, out, n);
}